// Round 5
// baseline (109.815 us; speedup 1.0000x reference)
//
#include <hip/hip_runtime.h>
#include <hip/hip_bf16.h>

#define B_ 8
#define C_ 64
#define N_ 4096
#define K_ 20
#define T_ 3
#define O_ 64
#define P_ 20
#define NK_ (N_ * K_) /* 81920 */
#define BN_EPS 1e-5f
#define PADW 68

// workspace layout (float offsets)
#define WS_FEATT 0                            // B*N*C      = 2,097,152
#define WS_WT (WS_FEATT + B_ * N_ * C_)       // 245,760 bf16 -> 122,880 float slots
#define WS_TAY (WS_WT + 122880)               // B*T*N*K    = 1,966,080
#define WS_RAW (WS_TAY + B_ * T_ * NK_)       // B*O*N      = 2,097,152
#define WS_PART (WS_RAW + B_ * O_ * N_)       // 512*64*2   =    65,536
#define WS_STATS (WS_PART + 512 * O_ * 2)     // 128

typedef __attribute__((ext_vector_type(8))) short short8;
typedef __attribute__((ext_vector_type(16))) float f32x16;

__device__ inline unsigned cvtpk_bf16(float lo, float hi) {
    unsigned r;
    asm volatile("v_cvt_pk_bf16_f32 %0, %1, %2" : "=v"(r) : "v"(lo), "v"(hi));
    return r;
}

union U128 {
    uint4 u;
    short8 s;
};
__device__ inline short8 as_short8(uint4 u) {
    U128 x;
    x.u = u;
    return x.s;
}

// K0: feat[b][c][n] -> featT[b][n][c]  (LDS tiled transpose, coalesced both sides)
__global__ void k_transpose_feat(const float* __restrict__ feat, float* __restrict__ featT) {
    __shared__ float t[64][65];
    int b = blockIdx.y;
    int n0 = blockIdx.x * 64;
    int lx = threadIdx.x & 63, ly = threadIdx.x >> 6;  // 256 threads
    const float* fp = feat + b * C_ * N_;
#pragma unroll
    for (int cc = 0; cc < 16; ++cc) {
        int c = ly * 16 + cc;
        t[c][lx] = fp[c * N_ + n0 + lx];
    }
    __syncthreads();
    float* op = featT + (b * N_ + n0) * C_;
#pragma unroll
    for (int u = 0; u < 16; ++u) {
        int n = ly * 16 + u;
        op[n * C_ + lx] = t[lx][n];
    }
}

// K5: pack conv_w into bf16 MFMA A-fragment order.
// frag id = ((k*3+t)*4+cc)*2+oh ; within frag: lane l (o = oh*32+(l&31)),
// 8 bf16 per lane: c = cc*16 + (l>>5)*8 + j
__global__ void k_pack_w(const float* __restrict__ cw, unsigned short* __restrict__ Wf) {
    int e = blockIdx.x * 256 + threadIdx.x;  // 245760 total
    int j = e & 7;
    int l = (e >> 3) & 63;
    int frag = e >> 9;
    int oh = frag & 1;
    int cc = (frag >> 1) & 3;
    int kt = frag >> 3;
    int t = kt % 3, k = kt / 3;
    int o = oh * 32 + (l & 31);
    int c = cc * 16 + (l >> 5) * 8 + j;
    float v = cw[o * (C_ * T_ * K_) + (c * T_ + t) * K_ + k];
    Wf[e] = (unsigned short)(cvtpk_bf16(v, v) & 0xffffu);
}

// K1: taylor. thread = b*NK + n*20+k  -> all weights reads perfectly coalesced.
__global__ void k_taylor(const float* __restrict__ W5, const float* __restrict__ gpc,
                         float* __restrict__ tay) {
    int tid = blockIdx.x * 256 + threadIdx.x;
    int b = tid / NK_;
    int nk = tid - b * NK_;
    const float X = gpc[b * 3 * NK_ + nk];
    const float Y = gpc[b * 3 * NK_ + NK_ + nk];
    const float Z = gpc[b * 3 * NK_ + 2 * NK_ + nk];
    float XX = X * X, YY = Y * Y, ZZ = Z * Z;
    float XY = X * Y, XZ = X * Z, YZ = Y * Z;
    float terms[20];
    terms[0] = 1.f; terms[1] = X;      terms[2] = Y;       terms[3] = Z;
    terms[4] = XX;  terms[5] = YY;     terms[6] = ZZ;
    terms[7] = XX * X; terms[8] = YY * Y; terms[9] = ZZ * Z;
    terms[10] = XY; terms[11] = XZ;    terms[12] = YZ;
    terms[13] = X * XY;
    terms[14] = X * XZ;
    terms[15] = Y * YZ;
    terms[16] = Y * XY;
    terms[17] = Z * XZ;
    terms[18] = Z * YZ;
    terms[19] = XY * Z;
    float a0 = 0.f, a1 = 0.f, a2 = 0.f;
    const float* wp = W5 + (size_t)b * P_ * T_ * NK_ + nk;
#pragma unroll
    for (int p = 0; p < P_; ++p) {
        float tp = terms[p];
        a0 += wp[0] * tp;
        a1 += wp[NK_] * tp;
        a2 += wp[2 * NK_] * tp;
        wp += 3 * NK_;
    }
    float* tp = tay + (size_t)b * T_ * NK_ + nk;
    tp[0] = a0;
    tp[NK_] = a1;
    tp[2 * NK_] = a2;
}

// K2: main contraction via bf16 MFMA 32x32x16.
// *** DIAGNOSTIC BUILD: accumulation loop runs TWICE, acc scaled by 0.5 at the
// end (identical result modulo one fp32 rounding). Purpose: push k_main above
// the harness's ~88us poison-fill dispatches so its rocprof counter row
// (MfmaUtil/VALUBusy/Occupancy/VGPR/bank-conflict/FETCH) becomes visible.
// Per-iteration behavior is byte-identical to the R4 structure. ***
__global__ __launch_bounds__(512, 4) void k_main(const float* __restrict__ featT,
                                                 const unsigned short* __restrict__ Wf,
                                                 const float* __restrict__ tay,
                                                 const int* __restrict__ idx,
                                                 float* __restrict__ raw,
                                                 float* __restrict__ part) {
    __shared__ float G[2][64][PADW];
    __shared__ union {
        struct {
            float tayS[3][K_][64];  // 15360 B
            int idxS[K_][64];       //  5120 B
        } s;
        float out[64][68];  // 17408 B epilogue merge buffer
    } su;

    // XCD-aware bijective swizzle (512 blocks, 8 XCDs -> one b per XCD's L2)
    const int bid0 = blockIdx.x;
    const int bid = (bid0 & 7) * 64 + (bid0 >> 3);
    const int b = bid >> 6;
    const int n0 = (bid & 63) << 6;
    const int tid = threadIdx.x;
    const int lane = tid & 63;
    const int wv = tid >> 6;  // 0..7
    const int wc = wv & 3;    // c-slice 16*wc
    const int wo = wv >> 2;   // o-half 32*wo
    const int nl = lane & 31;
    const int kf = lane >> 5;

    {  // stage idx + tay once (coalesced reads)
        const int* ip = idx + (b * N_ + n0) * K_;
        for (int e = tid; e < 64 * K_; e += 512) su.s.idxS[e % K_][e / K_] = ip[e];
#pragma unroll
        for (int t = 0; t < 3; ++t) {
            const float* tp = tay + ((size_t)(b * 3 + t) * N_ + n0) * K_;
            for (int e = tid; e < 64 * K_; e += 512) su.s.tayS[t][e % K_][e / K_] = tp[e];
        }
    }
    __syncthreads();

    f32x16 acc[2];
#pragma unroll
    for (int nh = 0; nh < 2; ++nh)
#pragma unroll
        for (int i = 0; i < 16; ++i) acc[nh][i] = 0.f;

    const float* fb = featT + (size_t)b * N_ * C_;
    const int r1 = tid >> 4, r2 = r1 + 32, sseg = tid & 15;

#pragma unroll 1
    for (int rep = 0; rep < 2; ++rep) {
        // prologue: load k=0 gather data (16-lane contiguous 256B runs)
        float4 st1 = *(const float4*)(fb + su.s.idxS[0][r1] * C_ + sseg * 4);
        float4 st2 = *(const float4*)(fb + su.s.idxS[0][r2] * C_ + sseg * 4);

        for (int k = 0; k < K_; ++k) {
            float* Gb = &G[k & 1][0][0];
            *(float4*)(Gb + r1 * PADW + sseg * 4) = st1;
            *(float4*)(Gb + r2 * PADW + sseg * 4) = st2;
            __syncthreads();  // G[k&1] published
            if (k + 1 < K_) {  // issue next gather; flies under this iter's compute
                st1 = *(const float4*)(fb + su.s.idxS[k + 1][r1] * C_ + sseg * 4);
                st2 = *(const float4*)(fb + su.s.idxS[k + 1][r2] * C_ + sseg * 4);
            }
            const float* row0 = Gb + nl * PADW + wc * 16 + kf * 8;
            const float* row1 = Gb + (nl + 32) * PADW + wc * 16 + kf * 8;
            float4 u0 = *(const float4*)row0, u1 = *(const float4*)(row0 + 4);
            float4 w0 = *(const float4*)row1, w1 = *(const float4*)(row1 + 4);
            float g0[8] = {u0.x, u0.y, u0.z, u0.w, u1.x, u1.y, u1.z, u1.w};
            float g1[8] = {w0.x, w0.y, w0.z, w0.w, w1.x, w1.y, w1.z, w1.w};
#pragma unroll
            for (int t = 0; t < 3; ++t) {
                uint4 ar = *(const uint4*)(Wf +
                                           (size_t)((((k * 3 + t) * 4 + wc) * 2 + wo) * 64 + lane) * 8);
                float tv0 = su.s.tayS[t][k][nl];
                float tv1 = su.s.tayS[t][k][nl + 32];
                unsigned p0[4], p1[4];
#pragma unroll
                for (int p = 0; p < 4; ++p) {
                    p0[p] = cvtpk_bf16(g0[2 * p] * tv0, g0[2 * p + 1] * tv0);
                    p1[p] = cvtpk_bf16(g1[2 * p] * tv1, g1[2 * p + 1] * tv1);
                }
                short8 bf0 = as_short8(make_uint4(p0[0], p0[1], p0[2], p0[3]));
                short8 bf1 = as_short8(make_uint4(p1[0], p1[1], p1[2], p1[3]));
                short8 a0 = as_short8(ar);
                acc[0] = __builtin_amdgcn_mfma_f32_32x32x16_bf16(a0, bf0, acc[0], 0, 0, 0);
                acc[1] = __builtin_amdgcn_mfma_f32_32x32x16_bf16(a0, bf1, acc[1], 0, 0, 0);
            }
        }
    }
    // undo the diagnostic doubling (exact scale by 2^-1)
#pragma unroll
    for (int nh = 0; nh < 2; ++nh)
#pragma unroll
        for (int i = 0; i < 16; ++i) acc[nh][i] *= 0.5f;

    __syncthreads();  // all LDS reads of su.s done; su.out overlays it
    // serialized cross-wave c-merge (deterministic); the two wo halves are disjoint rows
#pragma unroll 1
    for (int ww = 0; ww < 4; ++ww) {
        if (wc == ww) {
#pragma unroll
            for (int nh = 0; nh < 2; ++nh)
#pragma unroll
                for (int r = 0; r < 16; ++r) {
                    int row = wo * 32 + (r & 3) + ((r >> 2) << 3) + (kf << 2);
                    int col = nh * 32 + nl;
                    if (ww == 0)
                        su.out[row][col] = acc[nh][r];
                    else
                        su.out[row][col] += acc[nh][r];
                }
        }
        __syncthreads();
    }

    if (tid < 256) {  // write raw tile, coalesced float4
        int o = tid >> 2, seg = tid & 3;
        float4* dst = (float4*)(raw + ((b * O_ + o) * N_) + n0 + seg * 16);
        const float* srow = &su.out[o][seg * 16];
        dst[0] = *(const float4*)&srow[0];
        dst[1] = *(const float4*)&srow[4];
        dst[2] = *(const float4*)&srow[8];
        dst[3] = *(const float4*)&srow[12];
    }
    if (tid < 64) {  // per-block BN partial sums
        float s1 = 0.f, s2 = 0.f;
#pragma unroll 8
        for (int n = 0; n < 64; ++n) {
            float v = su.out[tid][n];
            s1 += v;
            s2 += v * v;
        }
        part[(bid * 64 + tid) * 2 + 0] = s1;
        part[(bid * 64 + tid) * 2 + 1] = s2;
    }
}

// K3: reduce 512 block-partials per channel -> scale/shift (deterministic)
__global__ void k_bnstats(const float* __restrict__ part, const float* __restrict__ gamma,
                          const float* __restrict__ beta, float* __restrict__ stats) {
    int o = blockIdx.x;
    int tid = threadIdx.x;
    __shared__ float s1s[256], s2s[256];
    float s1 = 0.f, s2 = 0.f;
    for (int j = tid; j < 512; j += 256) {
        s1 += part[(j * 64 + o) * 2 + 0];
        s2 += part[(j * 64 + o) * 2 + 1];
    }
    s1s[tid] = s1;
    s2s[tid] = s2;
    __syncthreads();
    for (int s = 128; s > 0; s >>= 1) {
        if (tid < s) {
            s1s[tid] += s1s[tid + s];
            s2s[tid] += s2s[tid + s];
        }
        __syncthreads();
    }
    if (tid == 0) {
        const float cnt = (float)(B_ * N_);
        float mean = s1s[0] / cnt;
        float var = s2s[0] / cnt - mean * mean;
        float sc = gamma[o] * rsqrtf(var + BN_EPS);
        stats[o * 2 + 0] = sc;
        stats[o * 2 + 1] = beta[o] - mean * sc;
    }
}

// K4: normalize + ReLU, float4
__global__ void k_finalize(const float* __restrict__ raw, const float* __restrict__ stats,
                           float* __restrict__ out) {
    int e = (blockIdx.x * 256 + threadIdx.x) * 4;
    int o = (e >> 12) & 63;
    float sc = stats[o * 2 + 0], sh = stats[o * 2 + 1];
    float4 v = *(const float4*)(raw + e);
    v.x = fmaxf(v.x * sc + sh, 0.f);
    v.y = fmaxf(v.y * sc + sh, 0.f);
    v.z = fmaxf(v.z * sc + sh, 0.f);
    v.w = fmaxf(v.w * sc + sh, 0.f);
    *(float4*)(out + e) = v;
}

extern "C" void kernel_launch(void* const* d_in, const int* in_sizes, int n_in,
                              void* d_out, int out_size, void* d_ws, size_t ws_size,
                              hipStream_t stream) {
    const float* feat = (const float*)d_in[0];
    const int* idx = (const int*)d_in[1];
    const float* gpc = (const float*)d_in[2];
    const float* weights = (const float*)d_in[3];
    const float* conv_w = (const float*)d_in[4];
    const float* gamma = (const float*)d_in[5];
    const float* beta = (const float*)d_in[6];
    float* out = (float*)d_out;
    float* ws = (float*)d_ws;

    float* featT = ws + WS_FEATT;
    unsigned short* Wf = (unsigned short*)(ws + WS_WT);
    float* tay = ws + WS_TAY;
    float* raw = ws + WS_RAW;
    float* part = ws + WS_PART;
    float* stats = ws + WS_STATS;

    hipLaunchKernelGGL(k_transpose_feat, dim3(N_ / 64, B_), dim3(256), 0, stream, feat, featT);
    hipLaunchKernelGGL(k_pack_w, dim3((K_ * T_ * C_ * O_) / 256), dim3(256), 0, stream, conv_w,
                       Wf);
    hipLaunchKernelGGL(k_taylor, dim3(B_ * NK_ / 256), dim3(256), 0, stream, weights, gpc, tay);
    hipLaunchKernelGGL(k_main, dim3(B_ * (N_ / 64)), dim3(512), 0, stream, featT, Wf, tay, idx,
                       raw, part);
    hipLaunchKernelGGL(k_bnstats, dim3(O_), dim3(256), 0, stream, part, gamma, beta, stats);
    hipLaunchKernelGGL(k_finalize, dim3(B_ * O_ * N_ / 4 / 256), dim3(256), 0, stream, raw, stats,
                       out);
}

// Round 7
// 74.595 us; speedup vs baseline: 1.4721x; 1.4721x over previous
//
#include <hip/hip_runtime.h>
#include <hip/hip_bf16.h>

#define B_ 8
#define C_ 64
#define N_ 4096
#define K_ 20
#define T_ 3
#define O_ 64
#define P_ 20
#define NK_ (N_ * K_) /* 81920 */
#define BN_EPS 1e-5f
#define PADW 68

// workspace layout (float offsets)
#define WS_FEATT 0                           // B*N*C      = 2,097,152
#define WS_WT (WS_FEATT + B_ * N_ * C_)      // 245,760 f16 -> 122,880 float slots
#define WS_RAW (WS_WT + 122880)              // B*O*N      = 2,097,152
#define WS_PART (WS_RAW + B_ * O_ * N_)      // 512*64*2   =    65,536
#define WS_STATS (WS_PART + 512 * O_ * 2)    // 128

typedef __attribute__((ext_vector_type(8))) _Float16 half8;
typedef __attribute__((ext_vector_type(2))) _Float16 half2v;
typedef __attribute__((ext_vector_type(2))) __fp16 fp16x2;
typedef __attribute__((ext_vector_type(16))) float f32x16;

union UH8 {
    uint4 u;
    half8 h;
    half2v h2[4];
};
union UH2 {
    unsigned u;
    half2v h;
    fp16x2 f;
};

// bit-cast the builtin's __fp16x2 result to our _Float16x2
__device__ inline half2v cvt_pkrtz(float a, float b) {
    UH2 x;
    x.f = __builtin_amdgcn_cvt_pkrtz(a, b);
    return x.h;
}
__device__ inline unsigned cvt_pkrtz_u(float a, float b) {
    UH2 x;
    x.f = __builtin_amdgcn_cvt_pkrtz(a, b);
    return x.u;
}

// K0: feat[b][c][n] -> featT[b][n][c]. XCD-aligned: block linear id %8 == b,
// matching k_main's consumer swizzle, so featT[b] lines land in XCD b's L2.
__global__ void k_transpose_feat(const float* __restrict__ feat, float* __restrict__ featT) {
    __shared__ float t[64][65];
    int bid = blockIdx.x;  // 512
    int b = bid & 7;
    int n0 = (bid >> 3) << 6;
    int lx = threadIdx.x & 63, ly = threadIdx.x >> 6;  // 256 threads
    const float* fp = feat + b * C_ * N_;
#pragma unroll
    for (int cc = 0; cc < 16; ++cc) {
        int c = ly * 16 + cc;
        t[c][lx] = fp[c * N_ + n0 + lx];
    }
    __syncthreads();
    float* op = featT + (b * N_ + n0) * C_;
#pragma unroll
    for (int u = 0; u < 16; ++u) {
        int n = ly * 16 + u;
        op[n * C_ + lx] = t[lx][n];
    }
}

// K5: pack conv_w into f16 MFMA A-fragment order.
// frag id = ((k*3+t)*4+cc)*2+oh ; within frag: lane l (o = oh*32+(l&31)),
// 8 f16 per lane: c = cc*16 + (l>>5)*8 + j
__global__ void k_pack_w(const float* __restrict__ cw, _Float16* __restrict__ Wh) {
    int e = blockIdx.x * 256 + threadIdx.x;  // 245760 total
    int j = e & 7;
    int l = (e >> 3) & 63;
    int frag = e >> 9;
    int oh = frag & 1;
    int cc = (frag >> 1) & 3;
    int kt = frag >> 3;
    int t = kt % 3, k = kt / 3;
    int o = oh * 32 + (l & 31);
    int c = cc * 16 + (l >> 5) * 8 + j;
    Wh[e] = (_Float16)cw[o * (C_ * T_ * K_) + (c * T_ + t) * K_ + k];
}

// K2: fused taylor + main contraction via f16 MFMA 32x32x16.
// Block = (b, 64-n tile), 512 threads = 8 waves: wc = c-slice 0..3, wo = o-half.
// Prologue computes this block's taylor slice from weights directly (no tay
// round-trip); loop stages gathers in double-buffered padded LDS, 1 barrier/iter.
__global__ __launch_bounds__(512, 4) void k_main(const float* __restrict__ featT,
                                                 const _Float16* __restrict__ Wh,
                                                 const float* __restrict__ weights,
                                                 const float* __restrict__ gpc,
                                                 const int* __restrict__ idx,
                                                 float* __restrict__ raw,
                                                 float* __restrict__ part) {
    __shared__ float G[2][64][PADW];  // 34816 B gather stage
    __shared__ union {
        struct {
            unsigned tayH[3][K_][64];  // 15360 B : half2(tay,tay)
            int idxS[K_][64];          //  5120 B
        } s;
        float out[64][68];  // 17408 B epilogue merge buffer
    } su;

    // XCD-aware bijective swizzle (512 blocks, 8 XCDs): XCD = bid0%8 = b
    const int bid0 = blockIdx.x;
    const int bid = (bid0 & 7) * 64 + (bid0 >> 3);
    const int b = bid >> 6;
    const int n0 = (bid & 63) << 6;
    const int tid = threadIdx.x;
    const int lane = tid & 63;
    const int wv = tid >> 6;  // 0..7
    const int wc = wv & 3;    // c-slice 16*wc
    const int wo = wv >> 2;   // o-half 32*wo
    const int nl = lane & 31;
    const int kf = lane >> 5;

    {  // stage idx (coalesced)
        const int* ip = idx + (b * N_ + n0) * K_;
        for (int e = tid; e < 64 * K_; e += 512) su.s.idxS[e % K_][e / K_] = ip[e];
    }
    {  // fused taylor: thread handles flat e = n*20+k (matches memory order ->
       // gpc and weights reads perfectly coalesced across the thread front)
        const float* gpcb = gpc + (size_t)b * 3 * NK_ + n0 * K_;
        const float* wb = weights + (size_t)b * P_ * T_ * NK_ + n0 * K_;
        for (int e = tid; e < 64 * K_; e += 512) {
            float X = gpcb[e];
            float Y = gpcb[NK_ + e];
            float Z = gpcb[2 * NK_ + e];
            float XX = X * X, YY = Y * Y, ZZ = Z * Z;
            float XY = X * Y, XZ = X * Z, YZ = Y * Z;
            float terms[20];
            terms[0] = 1.f; terms[1] = X;      terms[2] = Y;       terms[3] = Z;
            terms[4] = XX;  terms[5] = YY;     terms[6] = ZZ;
            terms[7] = XX * X; terms[8] = YY * Y; terms[9] = ZZ * Z;
            terms[10] = XY; terms[11] = XZ;    terms[12] = YZ;
            terms[13] = X * XY;
            terms[14] = X * XZ;
            terms[15] = Y * YZ;
            terms[16] = Y * XY;
            terms[17] = Z * XZ;
            terms[18] = Z * YZ;
            terms[19] = XY * Z;
            float a0 = 0.f, a1 = 0.f, a2 = 0.f;
            const float* wp = wb + e;
#pragma unroll
            for (int p = 0; p < P_; ++p) {
                float tp = terms[p];
                a0 += wp[0] * tp;
                a1 += wp[NK_] * tp;
                a2 += wp[2 * NK_] * tp;
                wp += 3 * NK_;
            }
            int n = e / K_, k = e - n * K_;
            su.s.tayH[0][k][n] = cvt_pkrtz_u(a0, a0);
            su.s.tayH[1][k][n] = cvt_pkrtz_u(a1, a1);
            su.s.tayH[2][k][n] = cvt_pkrtz_u(a2, a2);
        }
    }
    __syncthreads();

    f32x16 acc[2];
#pragma unroll
    for (int nh = 0; nh < 2; ++nh)
#pragma unroll
        for (int i = 0; i < 16; ++i) acc[nh][i] = 0.f;

    const float* fb = featT + (size_t)b * N_ * C_;
    const int r1 = tid >> 4, r2 = r1 + 32, sseg = tid & 15;

    // prologue: k=0 gather (16-lane contiguous 256B runs)
    float4 st1 = *(const float4*)(fb + su.s.idxS[0][r1] * C_ + sseg * 4);
    float4 st2 = *(const float4*)(fb + su.s.idxS[0][r2] * C_ + sseg * 4);

    for (int k = 0; k < K_; ++k) {
        float* Gb = &G[k & 1][0][0];
        *(float4*)(Gb + r1 * PADW + sseg * 4) = st1;
        *(float4*)(Gb + r2 * PADW + sseg * 4) = st2;
        __syncthreads();  // G[k&1] published
        if (k + 1 < K_) {  // next gather flies under this iter's compute
            st1 = *(const float4*)(fb + su.s.idxS[k + 1][r1] * C_ + sseg * 4);
            st2 = *(const float4*)(fb + su.s.idxS[k + 1][r2] * C_ + sseg * 4);
        }
        const float* row0 = Gb + nl * PADW + wc * 16 + kf * 8;
        const float* row1 = Gb + (nl + 32) * PADW + wc * 16 + kf * 8;
        float4 u0 = *(const float4*)row0, u1 = *(const float4*)(row0 + 4);
        float4 w0 = *(const float4*)row1, w1 = *(const float4*)(row1 + 4);
        // convert gathered rows to f16 pairs once per iter
        half2v h0[4], h1[4];
        h0[0] = cvt_pkrtz(u0.x, u0.y);
        h0[1] = cvt_pkrtz(u0.z, u0.w);
        h0[2] = cvt_pkrtz(u1.x, u1.y);
        h0[3] = cvt_pkrtz(u1.z, u1.w);
        h1[0] = cvt_pkrtz(w0.x, w0.y);
        h1[1] = cvt_pkrtz(w0.z, w0.w);
        h1[2] = cvt_pkrtz(w1.x, w1.y);
        h1[3] = cvt_pkrtz(w1.z, w1.w);
#pragma unroll
        for (int t = 0; t < 3; ++t) {
            UH8 ar;
            ar.u = *(const uint4*)(Wh +
                                   (size_t)((((k * 3 + t) * 4 + wc) * 2 + wo) * 64 + lane) * 8);
            UH2 tv0, tv1;
            tv0.u = su.s.tayH[t][k][nl];
            tv1.u = su.s.tayH[t][k][nl + 32];
            UH8 b0, b1;
#pragma unroll
            for (int i = 0; i < 4; ++i) {
                b0.h2[i] = h0[i] * tv0.h;  // v_pk_mul_f16
                b1.h2[i] = h1[i] * tv1.h;
            }
            acc[0] = __builtin_amdgcn_mfma_f32_32x32x16_f16(ar.h, b0.h, acc[0], 0, 0, 0);
            acc[1] = __builtin_amdgcn_mfma_f32_32x32x16_f16(ar.h, b1.h, acc[1], 0, 0, 0);
        }
    }

    __syncthreads();  // all LDS reads of su.s done; su.out overlays it
    // serialized cross-wave c-merge (deterministic); wo halves are disjoint rows
#pragma unroll 1
    for (int ww = 0; ww < 4; ++ww) {
        if (wc == ww) {
#pragma unroll
            for (int nh = 0; nh < 2; ++nh)
#pragma unroll
                for (int r = 0; r < 16; ++r) {
                    int row = wo * 32 + (r & 3) + ((r >> 2) << 3) + (kf << 2);
                    int col = nh * 32 + nl;
                    if (ww == 0)
                        su.out[row][col] = acc[nh][r];
                    else
                        su.out[row][col] += acc[nh][r];
                }
        }
        __syncthreads();
    }

    if (tid < 256) {  // write raw tile, coalesced float4
        int o = tid >> 2, seg = tid & 3;
        float4* dst = (float4*)(raw + ((b * O_ + o) * N_) + n0 + seg * 16);
        const float* srow = &su.out[o][seg * 16];
        dst[0] = *(const float4*)&srow[0];
        dst[1] = *(const float4*)&srow[4];
        dst[2] = *(const float4*)&srow[8];
        dst[3] = *(const float4*)&srow[12];
    }
    if (tid < 64) {  // per-block BN partial sums
        float s1 = 0.f, s2 = 0.f;
#pragma unroll 8
        for (int n = 0; n < 64; ++n) {
            float v = su.out[tid][n];
            s1 += v;
            s2 += v * v;
        }
        part[(bid * 64 + tid) * 2 + 0] = s1;
        part[(bid * 64 + tid) * 2 + 1] = s2;
    }
}

// K3: reduce 512 block-partials per channel -> scale/shift (deterministic)
__global__ void k_bnstats(const float* __restrict__ part, const float* __restrict__ gamma,
                          const float* __restrict__ beta, float* __restrict__ stats) {
    int o = blockIdx.x;
    int tid = threadIdx.x;
    __shared__ float s1s[256], s2s[256];
    float s1 = 0.f, s2 = 0.f;
    for (int j = tid; j < 512; j += 256) {
        s1 += part[(j * 64 + o) * 2 + 0];
        s2 += part[(j * 64 + o) * 2 + 1];
    }
    s1s[tid] = s1;
    s2s[tid] = s2;
    __syncthreads();
    for (int s = 128; s > 0; s >>= 1) {
        if (tid < s) {
            s1s[tid] += s1s[tid + s];
            s2s[tid] += s2s[tid + s];
        }
        __syncthreads();
    }
    if (tid == 0) {
        const float cnt = (float)(B_ * N_);
        float mean = s1s[0] / cnt;
        float var = s2s[0] / cnt - mean * mean;
        float sc = gamma[o] * rsqrtf(var + BN_EPS);
        stats[o * 2 + 0] = sc;
        stats[o * 2 + 1] = beta[o] - mean * sc;
    }
}

// K4: normalize + ReLU, float4
__global__ void k_finalize(const float* __restrict__ raw, const float* __restrict__ stats,
                           float* __restrict__ out) {
    int e = (blockIdx.x * 256 + threadIdx.x) * 4;
    int o = (e >> 12) & 63;
    float sc = stats[o * 2 + 0], sh = stats[o * 2 + 1];
    float4 v = *(const float4*)(raw + e);
    v.x = fmaxf(v.x * sc + sh, 0.f);
    v.y = fmaxf(v.y * sc + sh, 0.f);
    v.z = fmaxf(v.z * sc + sh, 0.f);
    v.w = fmaxf(v.w * sc + sh, 0.f);
    *(float4*)(out + e) = v;
}

extern "C" void kernel_launch(void* const* d_in, const int* in_sizes, int n_in,
                              void* d_out, int out_size, void* d_ws, size_t ws_size,
                              hipStream_t stream) {
    const float* feat = (const float*)d_in[0];
    const int* idx = (const int*)d_in[1];
    const float* gpc = (const float*)d_in[2];
    const float* weights = (const float*)d_in[3];
    const float* conv_w = (const float*)d_in[4];
    const float* gamma = (const float*)d_in[5];
    const float* beta = (const float*)d_in[6];
    float* out = (float*)d_out;
    float* ws = (float*)d_ws;

    float* featT = ws + WS_FEATT;
    _Float16* Wh = (_Float16*)(ws + WS_WT);
    float* raw = ws + WS_RAW;
    float* part = ws + WS_PART;
    float* stats = ws + WS_STATS;

    hipLaunchKernelGGL(k_transpose_feat, dim3(512), dim3(256), 0, stream, feat, featT);
    hipLaunchKernelGGL(k_pack_w, dim3((K_ * T_ * C_ * O_) / 256), dim3(256), 0, stream, conv_w,
                       Wh);
    hipLaunchKernelGGL(k_main, dim3(B_ * (N_ / 64)), dim3(512), 0, stream, featT, Wh, weights,
                       gpc, idx, raw, part);
    hipLaunchKernelGGL(k_bnstats, dim3(O_), dim3(256), 0, stream, part, gamma, beta, stats);
    hipLaunchKernelGGL(k_finalize, dim3(B_ * O_ * N_ / 4 / 256), dim3(256), 0, stream, raw, stats,
                       out);
}